// Round 4
// baseline (506.748 us; speedup 1.0000x reference)
//
#include <hip/hip_runtime.h>

#define THREADS 256
#define SCAN_CHUNK 2048   // 256 threads x 8 elems

// ---------------- CSR build ----------------
__global__ void k_zero(int* __restrict__ counts, int n) {
    int i = blockIdx.x * blockDim.x + threadIdx.x;
    if (i < n) counts[i] = 0;
}

__global__ void k_count(const int* __restrict__ dst, int* __restrict__ counts, int e) {
    int i = blockIdx.x * blockDim.x + threadIdx.x;
    if (i < e) atomicAdd(&counts[dst[i]], 1);
}

// inclusive scan of counts within 2048-chunks -> rowptr[i+1]; chunk totals -> bsum[b]
// also emits dinv[i] = rsqrt(counts[i]+1)  (self-loop)
__global__ __launch_bounds__(256) void k_scan1(const int* __restrict__ counts,
                                               int* __restrict__ rowptr,
                                               int* __restrict__ bsum,
                                               float* __restrict__ dinv, int n) {
    __shared__ int s[256];
    const int t = threadIdx.x;
    const int base = blockIdx.x * SCAN_CHUNK + t * 8;
    int c[8];
    int run = 0;
#pragma unroll
    for (int k = 0; k < 8; ++k) {
        int i = base + k;
        int cv = (i < n) ? counts[i] : 0;
        if (i < n) dinv[i] = rsqrtf((float)(cv + 1));
        run += cv;
        c[k] = run;  // running inclusive within thread
    }
    s[t] = run;
    __syncthreads();
    for (int off = 1; off < 256; off <<= 1) {
        int v = (t >= off) ? s[t - off] : 0;
        __syncthreads();
        s[t] += v;
        __syncthreads();
    }
    const int excl = s[t] - run;  // exclusive offset for this thread
#pragma unroll
    for (int k = 0; k < 8; ++k) {
        int i = base + k;
        if (i < n) rowptr[i + 1] = c[k] + excl;
    }
    if (t == 255) bsum[blockIdx.x] = s[255];
}

// exclusive scan of block sums (nb <= 256)
__global__ __launch_bounds__(256) void k_scan2(int* __restrict__ bsum, int nb) {
    __shared__ int s[256];
    const int t = threadIdx.x;
    int v0 = (t < nb) ? bsum[t] : 0;
    s[t] = v0;
    __syncthreads();
    for (int off = 1; off < 256; off <<= 1) {
        int v = (t >= off) ? s[t - off] : 0;
        __syncthreads();
        s[t] += v;
        __syncthreads();
    }
    if (t < nb) bsum[t] = s[t] - v0;  // exclusive
}

// add chunk offsets; produce fillptr[i] = rowptr[i] (start of bucket i)
__global__ __launch_bounds__(256) void k_scan3(const int* __restrict__ counts,
                                               int* __restrict__ rowptr,
                                               int* __restrict__ fillptr,
                                               const int* __restrict__ bsum, int n) {
    const int off = bsum[blockIdx.x];
    const int t = threadIdx.x;
#pragma unroll
    for (int k = 0; k < 8; ++k) {
        int i = blockIdx.x * SCAN_CHUNK + t + k * 256;
        if (i < n) {
            int incl = rowptr[i + 1] + off;
            rowptr[i + 1] = incl;
            fillptr[i] = incl - counts[i];
        }
    }
    if (blockIdx.x == 0 && t == 0) rowptr[0] = 0;
}

__global__ void k_fill(const int* __restrict__ src, const int* __restrict__ dst,
                       int* __restrict__ fillptr, int* __restrict__ csr_src, int e) {
    int i = blockIdx.x * blockDim.x + threadIdx.x;
    if (i < e) {
        int pos = atomicAdd(&fillptr[dst[i]], 1);
        csr_src[pos] = src[i];
    }
}

// ---------------- GEMM1: h1[n,128] = x[n,128] @ W1[128,128] ----------------
// 64 rows/block, 256 thr; thread = (colgroup cg=t&31 -> cols 4cg..4cg+3,
// rowgroup rg=t>>5 -> rows 8rg..8rg+7); K staged in two 64-halves.
__global__ __launch_bounds__(256) void k_gemm1(const float* __restrict__ x,
                                               const float* __restrict__ W,
                                               float* __restrict__ h, int n) {
    __shared__ float Wl[64 * 128];  // 32 KB, [kk][j]
    __shared__ float xl[64 * 64];   // 16 KB, [r][kk]
    const int t  = threadIdx.x;
    const int cg = t & 31;
    const int rg = t >> 5;
    const int base = blockIdx.x * 64;

    float acc[8][4];
#pragma unroll
    for (int i = 0; i < 8; ++i)
#pragma unroll
        for (int j = 0; j < 4; ++j) acc[i][j] = 0.0f;

    for (int ph = 0; ph < 2; ++ph) {
        __syncthreads();
        {
            const float4* Wg = (const float4*)(W + ph * 64 * 128);
            float4* Ws = (float4*)Wl;
#pragma unroll
            for (int i = 0; i < 8; ++i) Ws[t + 256 * i] = Wg[t + 256 * i];
        }
#pragma unroll
        for (int i = 0; i < 4; ++i) {
            const int idx = t + 256 * i;
            const int r = idx >> 4, c4 = idx & 15;
            const int row = base + r;
            float4 v = make_float4(0.f, 0.f, 0.f, 0.f);
            if (row < n) v = *(const float4*)(x + (size_t)row * 128 + ph * 64 + c4 * 4);
            *(float4*)(xl + r * 64 + c4 * 4) = v;
        }
        __syncthreads();

        for (int k4 = 0; k4 < 16; ++k4) {
            float wv[4][4];
#pragma unroll
            for (int kk = 0; kk < 4; ++kk) {
                const float4 w4 = *(const float4*)(Wl + (k4 * 4 + kk) * 128 + cg * 4);
                wv[kk][0] = w4.x; wv[kk][1] = w4.y; wv[kk][2] = w4.z; wv[kk][3] = w4.w;
            }
#pragma unroll
            for (int i = 0; i < 8; ++i) {
                const float4 x4 = *(const float4*)(xl + (rg * 8 + i) * 64 + k4 * 4);
                const float xs[4] = {x4.x, x4.y, x4.z, x4.w};
#pragma unroll
                for (int kk = 0; kk < 4; ++kk)
#pragma unroll
                    for (int j = 0; j < 4; ++j)
                        acc[i][j] = fmaf(xs[kk], wv[kk][j], acc[i][j]);
            }
        }
    }

#pragma unroll
    for (int i = 0; i < 8; ++i) {
        const int row = base + rg * 8 + i;
        if (row < n) {
            float4 r4 = make_float4(acc[i][0], acc[i][1], acc[i][2], acc[i][3]);
            *(float4*)(h + (size_t)row * 128 + cg * 4) = r4;
        }
    }
}

// ---------------- gather1 (feature-chunked): out1[d] = b1 + dd*(dd*h1[d] + sum dinv[s]*h1[s]) ----------------
// grid (ceil(n/4), 8): blockIdx.y = 16-feat chunk (3.2 MB slice, L2-resident).
// Wave = one node; lane = eg*16+f: 4 edges in flight, 64B coalesced reads/group.
__global__ __launch_bounds__(256) void k_gather1(const float* __restrict__ h1,
                                                 const int* __restrict__ rowptr,
                                                 const int* __restrict__ csr_src,
                                                 const float* __restrict__ dinv,
                                                 const float* __restrict__ b1,
                                                 float* __restrict__ out1, int n) {
    const int wave = threadIdx.x >> 6;
    const int lane = threadIdx.x & 63;
    const int d = blockIdx.x * 4 + wave;
    if (d >= n) return;
    const int f  = lane & 15;
    const int eg = lane >> 4;                 // 0..3
    const int col = blockIdx.y * 16 + f;
    const float dd = dinv[d];
    const int beg = rowptr[d], end = rowptr[d + 1];
    float acc = 0.0f;
    for (int p = beg + eg; p < end; p += 4) {
        const int s = __builtin_nontemporal_load(&csr_src[p]);
        const float w = dinv[s];
        acc = fmaf(w, h1[(size_t)s * 128 + col], acc);
    }
    acc += __shfl_xor(acc, 16);
    acc += __shfl_xor(acc, 32);
    if (eg == 0) {
        const float self = h1[(size_t)d * 128 + col];
        const float r = fmaf(dd, fmaf(dd, self, acc), b1[col]);
        __builtin_nontemporal_store(r, &out1[(size_t)d * 128 + col]);
    }
}

// ---------------- GEMM2: h2[n,40] = relu(out1)[n,128] @ W2[128,40] ----------------
__global__ __launch_bounds__(256) void k_gemm2(const float* __restrict__ h1,
                                               const float* __restrict__ W,
                                               float* __restrict__ h2, int n) {
    __shared__ float Wl[64 * 64];   // 16 KB, [kk][j] zero-padded j>=40
    __shared__ float xl[64 * 64];   // 16 KB, [r][kk]
    const int t  = threadIdx.x;
    const int cg = t & 15;
    const int rg = t >> 4;
    const int base = blockIdx.x * 64;

    float acc[4][4];
#pragma unroll
    for (int i = 0; i < 4; ++i)
#pragma unroll
        for (int j = 0; j < 4; ++j) acc[i][j] = 0.0f;

    for (int ph = 0; ph < 2; ++ph) {
        __syncthreads();
#pragma unroll
        for (int i = 0; i < 16; ++i) {
            const int idx = t + 256 * i;
            const int r = idx >> 6, c = idx & 63;
            Wl[idx] = (c < 40) ? W[(ph * 64 + r) * 40 + c] : 0.0f;
        }
#pragma unroll
        for (int i = 0; i < 4; ++i) {
            const int idx = t + 256 * i;
            const int r = idx >> 4, c4 = idx & 15;
            const int row = base + r;
            float4 v = make_float4(0.f, 0.f, 0.f, 0.f);
            if (row < n) {
                v = *(const float4*)(h1 + (size_t)row * 128 + ph * 64 + c4 * 4);
                v.x = fmaxf(v.x, 0.f); v.y = fmaxf(v.y, 0.f);
                v.z = fmaxf(v.z, 0.f); v.w = fmaxf(v.w, 0.f);
            }
            *(float4*)(xl + r * 64 + c4 * 4) = v;
        }
        __syncthreads();

        for (int k4 = 0; k4 < 16; ++k4) {
            float wv[4][4];
#pragma unroll
            for (int kk = 0; kk < 4; ++kk) {
                const float4 w4 = *(const float4*)(Wl + (k4 * 4 + kk) * 64 + cg * 4);
                wv[kk][0] = w4.x; wv[kk][1] = w4.y; wv[kk][2] = w4.z; wv[kk][3] = w4.w;
            }
#pragma unroll
            for (int i = 0; i < 4; ++i) {
                const float4 x4 = *(const float4*)(xl + (rg * 4 + i) * 64 + k4 * 4);
                const float xs[4] = {x4.x, x4.y, x4.z, x4.w};
#pragma unroll
                for (int kk = 0; kk < 4; ++kk)
#pragma unroll
                    for (int j = 0; j < 4; ++j)
                        acc[i][j] = fmaf(xs[kk], wv[kk][j], acc[i][j]);
            }
        }
    }

    if (cg < 10) {  // cols 4cg..4cg+3 < 40
#pragma unroll
        for (int i = 0; i < 4; ++i) {
            const int row = base + rg * 4 + i;
            if (row < n) {
                float4 r4 = make_float4(acc[i][0], acc[i][1], acc[i][2], acc[i][3]);
                *(float4*)(h2 + (size_t)row * 40 + cg * 4) = r4;
            }
        }
    }
}

// ---------------- gather2 (feature-chunked): 5 chunks of 8 feats ----------------
// Wave = one node; lane = eg*8+f: 8 edges in flight, 32B reads/group.
__global__ __launch_bounds__(256) void k_gather2(const float* __restrict__ h2,
                                                 const int* __restrict__ rowptr,
                                                 const int* __restrict__ csr_src,
                                                 const float* __restrict__ dinv,
                                                 const float* __restrict__ b2,
                                                 float* __restrict__ out, int n) {
    const int wave = threadIdx.x >> 6;
    const int lane = threadIdx.x & 63;
    const int d = blockIdx.x * 4 + wave;
    if (d >= n) return;
    const int f  = lane & 7;
    const int eg = lane >> 3;                 // 0..7
    const int col = blockIdx.y * 8 + f;
    const float dd = dinv[d];
    const int beg = rowptr[d], end = rowptr[d + 1];
    float acc = 0.0f;
    for (int p = beg + eg; p < end; p += 8) {
        const int s = __builtin_nontemporal_load(&csr_src[p]);
        acc = fmaf(dinv[s], h2[(size_t)s * 40 + col], acc);
    }
    acc += __shfl_xor(acc, 8);
    acc += __shfl_xor(acc, 16);
    acc += __shfl_xor(acc, 32);
    if (eg == 0) {
        const float self = h2[(size_t)d * 40 + col];
        const float r = fmaf(dd, fmaf(dd, self, acc), b2[col]);
        __builtin_nontemporal_store(r, &out[(size_t)d * 40 + col]);
    }
}

extern "C" void kernel_launch(void* const* d_in, const int* in_sizes, int n_in,
                              void* d_out, int out_size, void* d_ws, size_t ws_size,
                              hipStream_t stream) {
    const float* x  = (const float*)d_in[0];
    const int*   ei = (const int*)d_in[1];
    const float* W1 = (const float*)d_in[2];
    const float* b1 = (const float*)d_in[3];
    const float* W2 = (const float*)d_in[4];
    const float* b2 = (const float*)d_in[5];
    float* out = (float*)d_out;

    const int n = in_sizes[0] / 128;   // 50000
    const int e = in_sizes[1] / 2;     // 800000
    const int* src = ei;
    const int* dst = ei + e;

    const int n_pad = ((n + 63) / 64) * 64;
    const int e_pad = ((e + 63) / 64) * 64;

    // ws layout (4B units):
    //   dinv[n_pad] | rowptr[n_pad+64] | csr_src[e_pad] | h1[n*128] | out1[n*128]
    // counts/fillptr/bsum overlay the h1 region (dead before k_gemm1 writes h1);
    // h2 overlays h1 (h1 dead after k_gather1).
    float* ws      = (float*)d_ws;
    float* dinv    = ws;
    int*   rowptr  = (int*)(ws + n_pad);
    int*   csr_src = rowptr + n_pad + 64;
    float* h1      = (float*)(csr_src + e_pad);
    float* out1    = h1 + (size_t)n * 128;
    int*   counts  = (int*)h1;          // overlay
    int*   fillptr = counts + n_pad;    // overlay
    int*   bsum    = fillptr + n_pad;   // overlay
    float* h2      = h1;                // overlay

    const int nb_n    = (n + THREADS - 1) / THREADS;
    const int nb_e    = (e + THREADS - 1) / THREADS;
    const int nb_scan = (n + SCAN_CHUNK - 1) / SCAN_CHUNK;
    const int nb_rows = (n + 63) / 64;
    const int nb_g    = (n + 3) / 4;

    // CSR build
    k_zero <<<nb_n, THREADS, 0, stream>>>(counts, n);
    k_count<<<nb_e, THREADS, 0, stream>>>(dst, counts, e);
    k_scan1<<<nb_scan, 256, 0, stream>>>(counts, rowptr, bsum, dinv, n);
    k_scan2<<<1, 256, 0, stream>>>(bsum, nb_scan);
    k_scan3<<<nb_scan, 256, 0, stream>>>(counts, rowptr, fillptr, bsum, n);
    k_fill <<<nb_e, THREADS, 0, stream>>>(src, dst, fillptr, csr_src, e);

    // layer 1
    k_gemm1  <<<nb_rows, 256, 0, stream>>>(x, W1, h1, n);
    k_gather1<<<dim3(nb_g, 8), 256, 0, stream>>>(h1, rowptr, csr_src, dinv, b1, out1, n);

    // layer 2
    k_gemm2  <<<nb_rows, 256, 0, stream>>>(out1, W2, h2, n);
    k_gather2<<<dim3(nb_g, 5), 256, 0, stream>>>(h2, rowptr, csr_src, dinv, b2, out, n);
}

// Round 5
// 226.661 us; speedup vs baseline: 2.2357x; 2.2357x over previous
//
#include <hip/hip_runtime.h>
#include <hip/hip_fp16.h>

#define THREADS 256
#define SCAN_CHUNK 2048   // 256 threads x 8 elems

// ---------------- CSR build ----------------
__global__ void k_zero(int* __restrict__ counts, int n) {
    int i = blockIdx.x * blockDim.x + threadIdx.x;
    if (i < n) counts[i] = 0;
}

__global__ void k_count(const int* __restrict__ dst, int* __restrict__ counts, int e) {
    int i = blockIdx.x * blockDim.x + threadIdx.x;
    if (i < e) atomicAdd(&counts[dst[i]], 1);
}

// inclusive scan of counts within 2048-chunks -> rowptr[i+1]; chunk totals -> bsum[b]
// also emits dinv[i] = rsqrt(counts[i]+1)  (self-loop)
__global__ __launch_bounds__(256) void k_scan1(const int* __restrict__ counts,
                                               int* __restrict__ rowptr,
                                               int* __restrict__ bsum,
                                               float* __restrict__ dinv, int n) {
    __shared__ int s[256];
    const int t = threadIdx.x;
    const int base = blockIdx.x * SCAN_CHUNK + t * 8;
    int c[8];
    int run = 0;
#pragma unroll
    for (int k = 0; k < 8; ++k) {
        int i = base + k;
        int cv = (i < n) ? counts[i] : 0;
        if (i < n) dinv[i] = rsqrtf((float)(cv + 1));
        run += cv;
        c[k] = run;  // running inclusive within thread
    }
    s[t] = run;
    __syncthreads();
    for (int off = 1; off < 256; off <<= 1) {
        int v = (t >= off) ? s[t - off] : 0;
        __syncthreads();
        s[t] += v;
        __syncthreads();
    }
    const int excl = s[t] - run;  // exclusive offset for this thread
#pragma unroll
    for (int k = 0; k < 8; ++k) {
        int i = base + k;
        if (i < n) rowptr[i + 1] = c[k] + excl;
    }
    if (t == 255) bsum[blockIdx.x] = s[255];
}

// exclusive scan of block sums (nb <= 256)
__global__ __launch_bounds__(256) void k_scan2(int* __restrict__ bsum, int nb) {
    __shared__ int s[256];
    const int t = threadIdx.x;
    int v0 = (t < nb) ? bsum[t] : 0;
    s[t] = v0;
    __syncthreads();
    for (int off = 1; off < 256; off <<= 1) {
        int v = (t >= off) ? s[t - off] : 0;
        __syncthreads();
        s[t] += v;
        __syncthreads();
    }
    if (t < nb) bsum[t] = s[t] - v0;  // exclusive
}

// add chunk offsets; produce fillptr[i] = rowptr[i] (start of bucket i)
__global__ __launch_bounds__(256) void k_scan3(const int* __restrict__ counts,
                                               int* __restrict__ rowptr,
                                               int* __restrict__ fillptr,
                                               const int* __restrict__ bsum, int n) {
    const int off = bsum[blockIdx.x];
    const int t = threadIdx.x;
#pragma unroll
    for (int k = 0; k < 8; ++k) {
        int i = blockIdx.x * SCAN_CHUNK + t + k * 256;
        if (i < n) {
            int incl = rowptr[i + 1] + off;
            rowptr[i + 1] = incl;
            fillptr[i] = incl - counts[i];
        }
    }
    if (blockIdx.x == 0 && t == 0) rowptr[0] = 0;
}

__global__ void k_fill(const int* __restrict__ src, const int* __restrict__ dst,
                       int* __restrict__ fillptr, int* __restrict__ csr_src, int e) {
    int i = blockIdx.x * blockDim.x + threadIdx.x;
    if (i < e) {
        int pos = atomicAdd(&fillptr[dst[i]], 1);
        csr_src[pos] = src[i];
    }
}

// ---------------- GEMM1: g1[n,128](fp16) = dinv[row] * (x[n,128] @ W1[128,128]) ----------------
// 64 rows/block, 256 thr; thread = (cg=t&31 -> cols 4cg..4cg+3, rg=t>>5 -> rows 8rg..8rg+7).
__global__ __launch_bounds__(256) void k_gemm1(const float* __restrict__ x,
                                               const float* __restrict__ W,
                                               const float* __restrict__ dinv,
                                               __half2* __restrict__ g, int n) {
    __shared__ float Wl[64 * 128];  // 32 KB, [kk][j]
    __shared__ float xl[64 * 64];   // 16 KB, [r][kk]
    const int t  = threadIdx.x;
    const int cg = t & 31;
    const int rg = t >> 5;
    const int base = blockIdx.x * 64;

    float acc[8][4];
#pragma unroll
    for (int i = 0; i < 8; ++i)
#pragma unroll
        for (int j = 0; j < 4; ++j) acc[i][j] = 0.0f;

    for (int ph = 0; ph < 2; ++ph) {
        __syncthreads();
        {
            const float4* Wg = (const float4*)(W + ph * 64 * 128);
            float4* Ws = (float4*)Wl;
#pragma unroll
            for (int i = 0; i < 8; ++i) Ws[t + 256 * i] = Wg[t + 256 * i];
        }
#pragma unroll
        for (int i = 0; i < 4; ++i) {
            const int idx = t + 256 * i;
            const int r = idx >> 4, c4 = idx & 15;
            const int row = base + r;
            float4 v = make_float4(0.f, 0.f, 0.f, 0.f);
            if (row < n) v = *(const float4*)(x + (size_t)row * 128 + ph * 64 + c4 * 4);
            *(float4*)(xl + r * 64 + c4 * 4) = v;
        }
        __syncthreads();

        for (int k4 = 0; k4 < 16; ++k4) {
            float wv[4][4];
#pragma unroll
            for (int kk = 0; kk < 4; ++kk) {
                const float4 w4 = *(const float4*)(Wl + (k4 * 4 + kk) * 128 + cg * 4);
                wv[kk][0] = w4.x; wv[kk][1] = w4.y; wv[kk][2] = w4.z; wv[kk][3] = w4.w;
            }
#pragma unroll
            for (int i = 0; i < 8; ++i) {
                const float4 x4 = *(const float4*)(xl + (rg * 8 + i) * 64 + k4 * 4);
                const float xs[4] = {x4.x, x4.y, x4.z, x4.w};
#pragma unroll
                for (int kk = 0; kk < 4; ++kk)
#pragma unroll
                    for (int j = 0; j < 4; ++j)
                        acc[i][j] = fmaf(xs[kk], wv[kk][j], acc[i][j]);
            }
        }
    }

#pragma unroll
    for (int i = 0; i < 8; ++i) {
        const int row = base + rg * 8 + i;
        if (row < n) {
            const float dv = dinv[row];
            union { __half2 h[2]; uint2 u; } pk;
            pk.h[0] = __floats2half2_rn(acc[i][0] * dv, acc[i][1] * dv);
            pk.h[1] = __floats2half2_rn(acc[i][2] * dv, acc[i][3] * dv);
            *(uint2*)(g + (size_t)row * 64 + cg * 2) = pk.u;
        }
    }
}

// ---------------- gather1: out1[d] = b1 + dinv[d]*(g1[d] + sum_{s in N(d)} g1[s]) ----------------
// wave per node (4 waves/block); lane holds cols {2lane, 2lane+1}; 4-deep edge unroll.
__global__ __launch_bounds__(256) void k_gather1(const __half2* __restrict__ g,
                                                 const int* __restrict__ rowptr,
                                                 const int* __restrict__ csr_src,
                                                 const float* __restrict__ dinv,
                                                 const float* __restrict__ b1,
                                                 float* __restrict__ out1, int n) {
    const int wave = threadIdx.x >> 6;
    const int lane = threadIdx.x & 63;
    const int d = blockIdx.x * 4 + wave;
    if (d >= n) return;
    const int beg = rowptr[d], end = rowptr[d + 1];
    float ax = 0.f, ay = 0.f, bx = 0.f, by = 0.f;
    int p = beg;
    for (; p + 4 <= end; p += 4) {
        const int s0 = csr_src[p],     s1 = csr_src[p + 1];
        const int s2 = csr_src[p + 2], s3 = csr_src[p + 3];
        const __half2 v0 = g[(size_t)s0 * 64 + lane];
        const __half2 v1 = g[(size_t)s1 * 64 + lane];
        const __half2 v2 = g[(size_t)s2 * 64 + lane];
        const __half2 v3 = g[(size_t)s3 * 64 + lane];
        const float2 f0 = __half22float2(v0), f1 = __half22float2(v1);
        const float2 f2 = __half22float2(v2), f3 = __half22float2(v3);
        ax += f0.x + f2.x; ay += f0.y + f2.y;
        bx += f1.x + f3.x; by += f1.y + f3.y;
    }
    for (; p < end; ++p) {
        const int s0 = csr_src[p];
        const float2 f0 = __half22float2(g[(size_t)s0 * 64 + lane]);
        ax += f0.x; ay += f0.y;
    }
    // self term (g already carries dinv[d])
    const float2 fs = __half22float2(g[(size_t)d * 64 + lane]);
    ax += bx + fs.x;
    ay += by + fs.y;
    const float dd = dinv[d];
    const float2 bb = *(const float2*)(b1 + lane * 2);
    float2 r;
    r.x = fmaf(dd, ax, bb.x);
    r.y = fmaf(dd, ay, bb.y);
    *(float2*)(out1 + (size_t)d * 128 + lane * 2) = r;
}

// ---------------- GEMM2: g2[n,40](fp16) = dinv[row] * (relu(out1)[n,128] @ W2[128,40]) ----------------
__global__ __launch_bounds__(256) void k_gemm2(const float* __restrict__ h1,
                                               const float* __restrict__ W,
                                               const float* __restrict__ dinv,
                                               __half2* __restrict__ g, int n) {
    __shared__ float Wl[64 * 64];   // 16 KB, [kk][j] zero-padded j>=40
    __shared__ float xl[64 * 64];   // 16 KB, [r][kk]
    const int t  = threadIdx.x;
    const int cg = t & 15;
    const int rg = t >> 4;
    const int base = blockIdx.x * 64;

    float acc[4][4];
#pragma unroll
    for (int i = 0; i < 4; ++i)
#pragma unroll
        for (int j = 0; j < 4; ++j) acc[i][j] = 0.0f;

    for (int ph = 0; ph < 2; ++ph) {
        __syncthreads();
#pragma unroll
        for (int i = 0; i < 16; ++i) {
            const int idx = t + 256 * i;
            const int r = idx >> 6, c = idx & 63;
            Wl[idx] = (c < 40) ? W[(ph * 64 + r) * 40 + c] : 0.0f;
        }
#pragma unroll
        for (int i = 0; i < 4; ++i) {
            const int idx = t + 256 * i;
            const int r = idx >> 4, c4 = idx & 15;
            const int row = base + r;
            float4 v = make_float4(0.f, 0.f, 0.f, 0.f);
            if (row < n) {
                v = *(const float4*)(h1 + (size_t)row * 128 + ph * 64 + c4 * 4);
                v.x = fmaxf(v.x, 0.f); v.y = fmaxf(v.y, 0.f);
                v.z = fmaxf(v.z, 0.f); v.w = fmaxf(v.w, 0.f);
            }
            *(float4*)(xl + r * 64 + c4 * 4) = v;
        }
        __syncthreads();

        for (int k4 = 0; k4 < 16; ++k4) {
            float wv[4][4];
#pragma unroll
            for (int kk = 0; kk < 4; ++kk) {
                const float4 w4 = *(const float4*)(Wl + (k4 * 4 + kk) * 64 + cg * 4);
                wv[kk][0] = w4.x; wv[kk][1] = w4.y; wv[kk][2] = w4.z; wv[kk][3] = w4.w;
            }
#pragma unroll
            for (int i = 0; i < 4; ++i) {
                const float4 x4 = *(const float4*)(xl + (rg * 4 + i) * 64 + k4 * 4);
                const float xs[4] = {x4.x, x4.y, x4.z, x4.w};
#pragma unroll
                for (int kk = 0; kk < 4; ++kk)
#pragma unroll
                    for (int j = 0; j < 4; ++j)
                        acc[i][j] = fmaf(xs[kk], wv[kk][j], acc[i][j]);
            }
        }
    }

    if (cg < 10) {  // cols 4cg..4cg+3 < 40
#pragma unroll
        for (int i = 0; i < 4; ++i) {
            const int row = base + rg * 4 + i;
            if (row < n) {
                const float dv = dinv[row];
                union { __half2 h[2]; uint2 u; } pk;
                pk.h[0] = __floats2half2_rn(acc[i][0] * dv, acc[i][1] * dv);
                pk.h[1] = __floats2half2_rn(acc[i][2] * dv, acc[i][3] * dv);
                *(uint2*)(g + (size_t)row * 20 + cg * 2) = pk.u;
            }
        }
    }
}

// ---------------- gather2: out[d] = b2 + dinv[d]*(g2[d] + sum g2[s]) ----------------
// wave per node; lane = eg*32+f, f<20 active (cols 2f,2f+1); 2 edge-groups x 2-deep unroll.
__global__ __launch_bounds__(256) void k_gather2(const __half2* __restrict__ g,
                                                 const int* __restrict__ rowptr,
                                                 const int* __restrict__ csr_src,
                                                 const float* __restrict__ dinv,
                                                 const float* __restrict__ b2,
                                                 float* __restrict__ out, int n) {
    const int wave = threadIdx.x >> 6;
    const int lane = threadIdx.x & 63;
    const int d = blockIdx.x * 4 + wave;
    if (d >= n) return;
    const int f  = lane & 31;
    const int eg = lane >> 5;          // 0..1
    const int fc = (f < 20) ? f : 19;  // clamp so inactive lanes load safely
    const int beg = rowptr[d], end = rowptr[d + 1];
    float ax = 0.f, ay = 0.f;
    int p = beg + eg;
    for (; p + 2 < end; p += 4) {      // this eg handles p and p+2
        const int s0 = csr_src[p], s1 = csr_src[p + 2];
        const __half2 v0 = g[(size_t)s0 * 20 + fc];
        const __half2 v1 = g[(size_t)s1 * 20 + fc];
        const float2 f0 = __half22float2(v0), f1 = __half22float2(v1);
        ax += f0.x + f1.x;
        ay += f0.y + f1.y;
    }
    for (; p < end; p += 2) {
        const int s0 = csr_src[p];
        const float2 f0 = __half22float2(g[(size_t)s0 * 20 + fc]);
        ax += f0.x; ay += f0.y;
    }
    ax += __shfl_xor(ax, 32);
    ay += __shfl_xor(ay, 32);
    if (eg == 0 && f < 20) {
        const float2 fs = __half22float2(g[(size_t)d * 20 + f]);
        ax += fs.x; ay += fs.y;
        const float dd = dinv[d];
        const float2 bb = *(const float2*)(b2 + f * 2);
        float2 r;
        r.x = fmaf(dd, ax, bb.x);
        r.y = fmaf(dd, ay, bb.y);
        *(float2*)(out + (size_t)d * 40 + f * 2) = r;
    }
}

extern "C" void kernel_launch(void* const* d_in, const int* in_sizes, int n_in,
                              void* d_out, int out_size, void* d_ws, size_t ws_size,
                              hipStream_t stream) {
    const float* x  = (const float*)d_in[0];
    const int*   ei = (const int*)d_in[1];
    const float* W1 = (const float*)d_in[2];
    const float* b1 = (const float*)d_in[3];
    const float* W2 = (const float*)d_in[4];
    const float* b2 = (const float*)d_in[5];
    float* out = (float*)d_out;

    const int n = in_sizes[0] / 128;   // 50000
    const int e = in_sizes[1] / 2;     // 800000
    const int* src = ei;
    const int* dst = ei + e;

    const int n_pad = ((n + 63) / 64) * 64;
    const int e_pad = ((e + 63) / 64) * 64;

    // ws layout (4B units):
    //   dinv[n_pad] | rowptr[n_pad+64] | csr_src[e_pad] | g1[n_pad*64 half2] | out1[n*128]
    // counts/fillptr/bsum overlay g1 region (dead before k_gemm1 writes);
    // g2 (n*20 half2) overlays g1 (dead after k_gather1).
    float*   ws      = (float*)d_ws;
    float*   dinv    = ws;
    int*     rowptr  = (int*)(ws + n_pad);
    int*     csr_src = rowptr + n_pad + 64;
    __half2* g1      = (__half2*)(csr_src + e_pad);
    float*   out1    = (float*)(g1 + (size_t)n_pad * 64);
    int*     counts  = (int*)g1;        // overlay
    int*     fillptr = counts + n_pad;  // overlay
    int*     bsum    = fillptr + n_pad; // overlay
    __half2* g2      = g1;              // overlay

    const int nb_n    = (n + THREADS - 1) / THREADS;
    const int nb_e    = (e + THREADS - 1) / THREADS;
    const int nb_scan = (n + SCAN_CHUNK - 1) / SCAN_CHUNK;
    const int nb_rows = (n + 63) / 64;
    const int nb_g    = (n + 3) / 4;

    // CSR build
    k_zero <<<nb_n, THREADS, 0, stream>>>(counts, n);
    k_count<<<nb_e, THREADS, 0, stream>>>(dst, counts, e);
    k_scan1<<<nb_scan, 256, 0, stream>>>(counts, rowptr, bsum, dinv, n);
    k_scan2<<<1, 256, 0, stream>>>(bsum, nb_scan);
    k_scan3<<<nb_scan, 256, 0, stream>>>(counts, rowptr, fillptr, bsum, n);
    k_fill <<<nb_e, THREADS, 0, stream>>>(src, dst, fillptr, csr_src, e);

    // layer 1
    k_gemm1  <<<nb_rows, 256, 0, stream>>>(x, W1, dinv, g1, n);
    k_gather1<<<nb_g, 256, 0, stream>>>(g1, rowptr, csr_src, dinv, b1, out1, n);

    // layer 2
    k_gemm2  <<<nb_rows, 256, 0, stream>>>(out1, W2, dinv, g2, n);
    k_gather2<<<nb_g, 256, 0, stream>>>(g2, rowptr, csr_src, dinv, b2, out, n);
}